// Round 1
// baseline (6804.375 us; speedup 1.0000x reference)
//
#include <hip/hip_runtime.h>
#include <math.h>

// Problem constants (B, L, D, H, T) — fixed by the reference.
constexpr int Bn = 256;            // batch
constexpr int Ln = 256;            // seq len
constexpr int Dn = 768;            // input size
constexpr int Hn = 1024;           // hidden size
constexpr int Tn = 32;             // output steps

constexpr int K_A = Hn;            // 1024 : K of scores GEMM
constexpr int N_A = 3 * Ln;        // 768  : 3 heads x L
constexpr int K_C = 3 * Dn + Hn;   // 3328 : K of gates GEMM ([v|h])
constexpr int N_C = 4 * Hn;        // 4096 : 4 gates x H
constexpr int VH_LD = K_C;         // leading dim of [v|h] buffer

constexpr int ZA = 4;              // K-split of scores GEMM (256 each)
constexpr int ZC = 2;              // K-split of gates GEMM (1664 each)

// ---- workspace layout (float offsets) ----
constexpr size_t OFF_WTA   = 0;                              // [K_A][N_A]   WcatT for scores
constexpr size_t OFF_WTC   = OFF_WTA + (size_t)K_A * N_A;    // [K_C][N_C]   [W_ih|W_hh]^T
constexpr size_t OFF_BIASC = OFF_WTC + (size_t)K_C * N_C;    // [N_C]        b_ih + b_hh
constexpr size_t OFF_B123  = OFF_BIASC + N_C;                // [768]        b1|b2|b3
constexpr size_t OFF_VH    = OFF_B123 + N_A;                 // [B][3328]    [v | h]
constexpr size_t OFF_C     = OFF_VH + (size_t)Bn * VH_LD;    // [B][H]       cell state
constexpr size_t OFF_LP    = OFF_C + (size_t)Bn * Hn;        // [ZA][B][768] score partials
constexpr size_t OFF_GP    = OFF_LP + (size_t)ZA * Bn * N_A; // [ZC][B][4096] gate partials
constexpr size_t WS_FLOATS = OFF_GP + (size_t)ZC * Bn * N_C; // ~18.4M floats = 74 MB

// ============================ prep kernels (once per call) ============================

__global__ __launch_bounds__(256) void prep_wta(const float* __restrict__ W1,
                                                const float* __restrict__ W2,
                                                const float* __restrict__ W3,
                                                float* __restrict__ WT_A) {
    int id = blockIdx.x * 256 + threadIdx.x;          // over K_A*N_A = 786432
    int d = id / N_A, c = id % N_A;                   // c = head*256 + l
    int k = c >> 8, l = c & 255;
    const float* Wk = (k == 0) ? W1 : ((k == 1) ? W2 : W3);
    WT_A[id] = Wk[l * Hn + d];
}

__global__ __launch_bounds__(256) void prep_wtc(const float* __restrict__ W_ih,
                                                const float* __restrict__ W_hh,
                                                float* __restrict__ WT_C) {
    int id = blockIdx.x * 256 + threadIdx.x;          // over K_C*N_C = 13631488
    int j = id >> 12, n = id & 4095;                  // N_C = 4096
    WT_C[id] = (j < 3 * Dn) ? W_ih[(size_t)n * (3 * Dn) + j]
                            : W_hh[(size_t)n * Hn + (j - 3 * Dn)];
}

__global__ __launch_bounds__(256) void prep_state(const float* __restrict__ h0,
                                                  const float* __restrict__ c0,
                                                  const float* __restrict__ b_ih,
                                                  const float* __restrict__ b_hh,
                                                  const float* __restrict__ b1,
                                                  const float* __restrict__ b2,
                                                  const float* __restrict__ b3,
                                                  float* __restrict__ v_h,
                                                  float* __restrict__ c,
                                                  float* __restrict__ biasC,
                                                  float* __restrict__ bias123) {
    int gid = blockIdx.x * 256 + threadIdx.x;         // grid covers B*H = 262144
    if (gid < Bn * Hn) {
        int b = gid >> 10, j = gid & 1023;
        v_h[(size_t)b * VH_LD + 3 * Dn + j] = h0[gid];
        c[gid] = c0[gid];
    }
    if (gid < N_C) biasC[gid] = b_ih[gid] + b_hh[gid];
    if (gid < N_A) {
        int k = gid >> 8, l = gid & 255;
        bias123[gid] = (k == 0 ? b1 : (k == 1 ? b2 : b3))[l];
    }
}

// ============================ fp32 tiled GEMM ============================
// C_partial[z] = A[:, z*KSUB : (z+1)*KSUB] @ B[z*KSUB : (z+1)*KSUB, :]
// 64x64 tile, KT=16, 256 threads, 4x4 per thread. Consumers sum partials + bias.
template <int KSUB>
__global__ __launch_bounds__(256) void gemm64(const float* __restrict__ A, int lda,
                                              const float* __restrict__ Bm, int ldb,
                                              float* __restrict__ C, int ldc, int Mtot) {
    __shared__ float As[16][68];   // [k][m], padded: conflict-light transposed store
    __shared__ float Bs[16][64];   // [k][n]

    const int t  = threadIdx.x;
    const int bm = blockIdx.y * 64;
    const int bn = blockIdx.x * 64;
    A  += (size_t)blockIdx.z * KSUB;                 // column offset into A
    Bm += (size_t)blockIdx.z * KSUB * ldb;           // row offset into B
    C  += (size_t)blockIdx.z * Mtot * ldc;           // partial-output buffer

    const int tm = t >> 4;       // 0..15 -> output rows tm*4..tm*4+3
    const int tn = t & 15;       // 0..15 -> output cols tn*4..tn*4+3

    float acc[4][4] = {};

    for (int k0 = 0; k0 < KSUB; k0 += 16) {
        __syncthreads();
#pragma unroll
        for (int p = 0; p < 4; ++p) {
            int i  = p * 256 + t;
            int am = i >> 4, ak = i & 15;            // A tile element (m, k)
            As[ak][am] = A[(size_t)(bm + am) * lda + k0 + ak];
            int bk = i >> 6, bn2 = i & 63;           // B tile element (k, n)
            Bs[bk][bn2] = Bm[(size_t)(k0 + bk) * ldb + bn + bn2];
        }
        __syncthreads();
#pragma unroll
        for (int kk = 0; kk < 16; ++kk) {
            const float4 a4 = *reinterpret_cast<const float4*>(&As[kk][tm * 4]);
            const float4 b4 = *reinterpret_cast<const float4*>(&Bs[kk][tn * 4]);
            float av[4] = {a4.x, a4.y, a4.z, a4.w};
            float bv[4] = {b4.x, b4.y, b4.z, b4.w};
#pragma unroll
            for (int i = 0; i < 4; ++i)
#pragma unroll
                for (int j = 0; j < 4; ++j) acc[i][j] += av[i] * bv[j];
        }
    }

#pragma unroll
    for (int i = 0; i < 4; ++i) {
        float4 o = make_float4(acc[i][0], acc[i][1], acc[i][2], acc[i][3]);
        *reinterpret_cast<float4*>(&C[(size_t)(bm + tm * 4 + i) * ldc + bn + tn * 4]) = o;
    }
}

// ============================ softmax + attention values ============================
// One block per batch b (768 threads = 12 waves). Sums score partials + bias,
// softmax per head (3 waves), then v[b, k*768+d] = sum_l a[k][l] * x[b][l][d].
__global__ __launch_bounds__(768) void attn_kernel(const float* __restrict__ lp,      // [ZA][B][768]
                                                   const float* __restrict__ bias123, // [768]
                                                   const float* __restrict__ x,       // [B][L][D]
                                                   float* __restrict__ v_h) {         // [B][3328]
    __shared__ float sc[3 * Ln];   // logits -> softmax probs, [head*256 + l]

    const int b = blockIdx.x;
    const int t = threadIdx.x;

    // reduce K-split partials + bias
    {
        float v = bias123[t];
#pragma unroll
        for (int s = 0; s < ZA; ++s) v += lp[((size_t)s * Bn + b) * N_A + t];
        sc[t] = v;
    }
    __syncthreads();

    // per-head softmax over L=256: wave w (<3) owns head w
    const int w = t >> 6, lane = t & 63;
    if (w < 3) {
        float vals[4];
        float m = -3.4e38f;
#pragma unroll
        for (int p = 0; p < 4; ++p) {
            vals[p] = sc[w * 256 + lane + p * 64];
            m = fmaxf(m, vals[p]);
        }
#pragma unroll
        for (int off = 32; off; off >>= 1) m = fmaxf(m, __shfl_xor(m, off));
        float ssum = 0.f;
#pragma unroll
        for (int p = 0; p < 4; ++p) {
            vals[p] = expf(vals[p] - m);
            ssum += vals[p];
        }
#pragma unroll
        for (int off = 32; off; off >>= 1) ssum += __shfl_xor(ssum, off);
        const float inv = 1.0f / ssum;
#pragma unroll
        for (int p = 0; p < 4; ++p) sc[w * 256 + lane + p * 64] = vals[p] * inv;
    }
    __syncthreads();

    // weighted sum over sequence: thread t owns column d=t of all 3 heads
    float acc0 = 0.f, acc1 = 0.f, acc2 = 0.f;
    const float* xb = x + (size_t)b * Ln * Dn;
#pragma unroll 8
    for (int l = 0; l < Ln; ++l) {
        const float xv = xb[(size_t)l * Dn + t];
        acc0 += sc[l] * xv;
        acc1 += sc[256 + l] * xv;
        acc2 += sc[512 + l] * xv;
    }
    float* vb = v_h + (size_t)b * VH_LD;
    vb[t]           = acc0;
    vb[Dn + t]      = acc1;
    vb[2 * Dn + t]  = acc2;
}

// ============================ LSTM cell elementwise ============================
__global__ __launch_bounds__(256) void lstm_kernel(const float* __restrict__ gp,    // [ZC][B][4096]
                                                   const float* __restrict__ biasC, // [4096]
                                                   float* __restrict__ c,           // [B][H]
                                                   float* __restrict__ v_h,         // [B][3328]
                                                   float* __restrict__ out,         // [B][T][H]
                                                   int tstep) {
    const int gid = blockIdx.x * 256 + threadIdx.x;  // B*H
    const int b = gid >> 10, j = gid & 1023;
    const float* g0 = gp + (size_t)b * N_C;
    const float* g1 = gp + (size_t)Bn * N_C + (size_t)b * N_C;

    const float ig = g0[j]            + g1[j]            + biasC[j];
    const float fg = g0[Hn + j]       + g1[Hn + j]       + biasC[Hn + j];
    const float gg = g0[2 * Hn + j]   + g1[2 * Hn + j]   + biasC[2 * Hn + j];
    const float og = g0[3 * Hn + j]   + g1[3 * Hn + j]   + biasC[3 * Hn + j];

    const float i_s = 1.f / (1.f + expf(-ig));
    const float f_s = 1.f / (1.f + expf(-fg));
    const float o_s = 1.f / (1.f + expf(-og));
    const float g_t = tanhf(gg);

    const float ci = c[gid];
    const float cn = f_s * ci + i_s * g_t;
    const float hn = o_s * tanhf(cn);

    c[gid] = cn;
    v_h[(size_t)b * VH_LD + 3 * Dn + j] = hn;
    out[((size_t)b * Tn + tstep) * Hn + j] = hn;
}

// ============================ launch ============================

extern "C" void kernel_launch(void* const* d_in, const int* in_sizes, int n_in,
                              void* d_out, int out_size, void* d_ws, size_t ws_size,
                              hipStream_t stream) {
    const float* x    = (const float*)d_in[0];
    const float* h0   = (const float*)d_in[1];
    const float* c0   = (const float*)d_in[2];
    const float* W1   = (const float*)d_in[3];
    const float* b1   = (const float*)d_in[4];
    const float* W2   = (const float*)d_in[5];
    const float* b2   = (const float*)d_in[6];
    const float* W3   = (const float*)d_in[7];
    const float* b3   = (const float*)d_in[8];
    const float* W_ih = (const float*)d_in[9];
    const float* W_hh = (const float*)d_in[10];
    const float* b_ih = (const float*)d_in[11];
    const float* b_hh = (const float*)d_in[12];
    float* out = (float*)d_out;

    float* ws      = (float*)d_ws;
    float* WT_A    = ws + OFF_WTA;
    float* WT_C    = ws + OFF_WTC;
    float* biasC   = ws + OFF_BIASC;
    float* bias123 = ws + OFF_B123;
    float* v_h     = ws + OFF_VH;
    float* cbuf    = ws + OFF_C;
    float* lp      = ws + OFF_LP;
    float* gp      = ws + OFF_GP;

    // ---- once-per-call prep ----
    prep_wta<<<(K_A * N_A) / 256, 256, 0, stream>>>(W1, W2, W3, WT_A);
    prep_wtc<<<((size_t)K_C * N_C) / 256, 256, 0, stream>>>(W_ih, W_hh, WT_C);
    prep_state<<<(Bn * Hn) / 256, 256, 0, stream>>>(h0, c0, b_ih, b_hh, b1, b2, b3,
                                                    v_h, cbuf, biasC, bias123);

    // ---- recurrent steps ----
    const float* h_in = v_h + 3 * Dn;  // h lives at v_h[:, 2304:3328]
    for (int t = 0; t < Tn; ++t) {
        // Phase A: score logits = h @ WcatT  (K=1024 split 4x256)
        gemm64<K_A / ZA><<<dim3(N_A / 64, Bn / 64, ZA), 256, 0, stream>>>(
            h_in, VH_LD, WT_A, N_A, lp, N_A, Bn);
        // Phase B: softmax + attention values -> v_h[:, 0:2304]
        attn_kernel<<<Bn, 768, 0, stream>>>(lp, bias123, x, v_h);
        // Phase C: gates = [v|h] @ [W_ih|W_hh]^T  (K=3328 split 2x1664)
        gemm64<K_C / ZC><<<dim3(N_C / 64, Bn / 64, ZC), 256, 0, stream>>>(
            v_h, VH_LD, WT_C, N_C, gp, N_C, Bn);
        // Phase D: LSTM cell, write h into v_h and out
        lstm_kernel<<<(Bn * Hn) / 256, 256, 0, stream>>>(gp, biasC, cbuf, v_h, out, t);
    }

    (void)in_sizes; (void)n_in; (void)out_size; (void)ws_size;
}

// Round 2
// 3284.991 us; speedup vs baseline: 2.0714x; 2.0714x over previous
//
#include <hip/hip_runtime.h>
#include <math.h>

// Problem constants (B, L, D, H, T) — fixed by the reference.
constexpr int Bn = 256;            // batch
constexpr int Ln = 256;            // seq len
constexpr int Dn = 768;            // input size
constexpr int Hn = 1024;           // hidden size
constexpr int Tn = 32;             // output steps

constexpr int K_A = Hn;            // 1024 : K of scores GEMM
constexpr int N_A = 3 * Ln;        // 768  : 3 heads x L
constexpr int K_C = 3 * Dn + Hn;   // 3328 : K of gates GEMM ([v|h])
constexpr int N_C = 4 * Hn;        // 4096 : 4 gates x H

constexpr int ZA = 4;              // K-split of scores GEMM (4 x 256)
constexpr int ZC = 8;              // K-split of gates GEMM (8 x 416)

typedef unsigned short u16;
typedef short bf16x8 __attribute__((ext_vector_type(8)));  // 8 bf16 = 4 VGPRs
typedef float f32x4 __attribute__((ext_vector_type(4)));

// ---- workspace layout (byte offsets) ----
constexpr size_t BY_WCHI  = 0;                                   // [N_C][K_C] bf16 hi
constexpr size_t BY_WCLO  = BY_WCHI  + (size_t)N_C * K_C * 2;    // [N_C][K_C] bf16 lo
constexpr size_t BY_WAHI  = BY_WCLO  + (size_t)N_C * K_C * 2;    // [N_A][K_A] bf16 hi
constexpr size_t BY_WALO  = BY_WAHI  + (size_t)N_A * K_A * 2;    // [N_A][K_A] bf16 lo
constexpr size_t BY_AHI   = BY_WALO  + (size_t)N_A * K_A * 2;    // [B][K_C]  activations hi
constexpr size_t BY_ALO   = BY_AHI   + (size_t)Bn * K_C * 2;     // [B][K_C]  activations lo
constexpr size_t BY_BIASC = BY_ALO   + (size_t)Bn * K_C * 2;     // [N_C] f32
constexpr size_t BY_B123  = BY_BIASC + (size_t)N_C * 4;          // [N_A] f32
constexpr size_t BY_C     = BY_B123  + (size_t)N_A * 4;          // [B][H] f32 cell
constexpr size_t BY_LP    = BY_C     + (size_t)Bn * Hn * 4;      // [ZA][B][N_A] f32
constexpr size_t BY_GP    = BY_LP    + (size_t)ZA * Bn * N_A * 4;// [ZC][B][N_C] f32

// ---- bf16 split helpers ----
__device__ inline u16 f2bf(float f) {
    unsigned int u = __float_as_uint(f);
    u = (u + 0x7fff + ((u >> 16) & 1)) >> 16;   // round-to-nearest-even
    return (u16)u;
}
__device__ inline float bf2f(u16 s) { return __uint_as_float((unsigned int)s << 16); }
__device__ inline void split2(float a, u16& hi, u16& lo) {
    hi = f2bf(a);
    lo = f2bf(a - bf2f(hi));
}

// ============================ prep kernels (once per call) ============================

__global__ __launch_bounds__(256) void prep_wc(const float* __restrict__ W_ih,
                                               const float* __restrict__ W_hh,
                                               u16* __restrict__ Whi, u16* __restrict__ Wlo) {
    size_t id = (size_t)blockIdx.x * 256 + threadIdx.x;   // over N_C*K_C
    int n = (int)(id / K_C), j = (int)(id % K_C);
    float v = (j < 3 * Dn) ? W_ih[(size_t)n * (3 * Dn) + j]
                           : W_hh[(size_t)n * Hn + (j - 3 * Dn)];
    split2(v, Whi[id], Wlo[id]);
}

__global__ __launch_bounds__(256) void prep_wa(const float* __restrict__ W1,
                                               const float* __restrict__ W2,
                                               const float* __restrict__ W3,
                                               u16* __restrict__ Whi, u16* __restrict__ Wlo) {
    int id = blockIdx.x * 256 + threadIdx.x;              // over N_A*K_A
    int c = id >> 10, d = id & 1023;                      // row c = head*256+l
    int k = c >> 8, l = c & 255;
    const float* Wk = (k == 0) ? W1 : ((k == 1) ? W2 : W3);
    split2(Wk[l * Hn + d], Whi[id], Wlo[id]);
}

__global__ __launch_bounds__(256) void prep_state(const float* __restrict__ h0,
                                                  const float* __restrict__ c0,
                                                  const float* __restrict__ b_ih,
                                                  const float* __restrict__ b_hh,
                                                  const float* __restrict__ b1,
                                                  const float* __restrict__ b2,
                                                  const float* __restrict__ b3,
                                                  u16* __restrict__ Ahi, u16* __restrict__ Alo,
                                                  float* __restrict__ c,
                                                  float* __restrict__ biasC,
                                                  float* __restrict__ bias123) {
    int gid = blockIdx.x * 256 + threadIdx.x;             // grid covers B*H
    int b = gid >> 10, j = gid & 1023;
    split2(h0[gid], Ahi[(size_t)b * K_C + 3 * Dn + j], Alo[(size_t)b * K_C + 3 * Dn + j]);
    c[gid] = c0[gid];
    if (gid < N_C) biasC[gid] = b_ih[gid] + b_hh[gid];
    if (gid < N_A) {
        int k = gid >> 8, l = gid & 255;
        bias123[gid] = (k == 0 ? b1 : (k == 1 ? b2 : b3))[l];
    }
}

// ============================ split-bf16 MFMA GEMM ============================
// Cp[z] = Ahi*Whi^T + Ahi*Wlo^T + Alo*Whi^T over K-slice z (fp32-grade accuracy).
// A: [M][lda] bf16 rows, W: [N][ldw] bf16 rows (i.e. B^T layout). 128x128 tile,
// BK=32, 4 waves (64x64 quadrant each), global_load_lds(16B) staging, m97-style.
__device__ inline void gload16(const u16* g, u16* l) {
    __builtin_amdgcn_global_load_lds(
        (const __attribute__((address_space(1))) unsigned int*)g,
        (__attribute__((address_space(3))) unsigned int*)l, 16, 0, 0);
}

__global__ __launch_bounds__(256) void gemm_mfma3(const u16* __restrict__ Ahi,
                                                  const u16* __restrict__ Alo, int lda,
                                                  const u16* __restrict__ Whi,
                                                  const u16* __restrict__ Wlo, int ldw,
                                                  float* __restrict__ Cp, int ldc, int mtot,
                                                  int ksub, int nkstep) {
    __shared__ u16 sAhi[128 * 32];
    __shared__ u16 sAlo[128 * 32];
    __shared__ u16 sWhi[128 * 32];
    __shared__ u16 sWlo[128 * 32];

    const int t = threadIdx.x;
    const int w = t >> 6, lane = t & 63;
    const int bm = blockIdx.y * 128;
    const int bn = blockIdx.x * 128;
    const int k00 = blockIdx.z * ksub;
    Cp += (size_t)blockIdx.z * mtot * ldc;

    // staging role: wave w owns one of the 4 tiles
    const u16* gsrc;
    u16* ldst;
    int ld, rb;
    if      (w == 0) { gsrc = Ahi; ldst = sAhi; ld = lda; rb = bm; }
    else if (w == 1) { gsrc = Alo; ldst = sAlo; ld = lda; rb = bm; }
    else if (w == 2) { gsrc = Whi; ldst = sWhi; ld = ldw; rb = bn; }
    else             { gsrc = Wlo; ldst = sWlo; ld = ldw; rb = bn; }
    const int srow = lane >> 2;          // 0..15 within 16-row chunk
    const int scol = (lane & 3) * 8;     // k-offset of this lane's 16B

    const int wrow = (w >> 1) * 64;      // wave's output quadrant
    const int wcol = (w & 1) * 64;
    const int fr = lane & 15;            // fragment row/col within 16
    const int kc = (lane >> 4) * 8;      // fragment k-chunk

    f32x4 acc[4][4] = {};

    for (int ks = 0; ks < nkstep; ++ks) {
        const int k0 = k00 + ks * 32;
        // ---- stage this k-step's 4 tiles (8 x 1KB per wave) ----
#pragma unroll
        for (int i = 0; i < 8; ++i) {
            const u16* p = gsrc + (size_t)(rb + i * 16 + srow) * ld + k0 + scol;
            gload16(p, ldst + i * 512);
        }
        __syncthreads();   // compiler emits vmcnt(0) before barrier

        // ---- LDS -> fragments ----
        bf16x8 ah[4], al[4], wh[4], wl[4];
#pragma unroll
        for (int f = 0; f < 4; ++f) {
            ah[f] = *(const bf16x8*)&sAhi[(wrow + f * 16 + fr) * 32 + kc];
            al[f] = *(const bf16x8*)&sAlo[(wrow + f * 16 + fr) * 32 + kc];
            wh[f] = *(const bf16x8*)&sWhi[(wcol + f * 16 + fr) * 32 + kc];
            wl[f] = *(const bf16x8*)&sWlo[(wcol + f * 16 + fr) * 32 + kc];
        }
        // ---- 48 MFMA: hi*hi + hi*lo + lo*hi ----
#pragma unroll
        for (int i = 0; i < 4; ++i)
#pragma unroll
            for (int j = 0; j < 4; ++j)
                acc[i][j] = __builtin_amdgcn_mfma_f32_16x16x32_bf16(ah[i], wh[j], acc[i][j], 0, 0, 0);
#pragma unroll
        for (int i = 0; i < 4; ++i)
#pragma unroll
            for (int j = 0; j < 4; ++j)
                acc[i][j] = __builtin_amdgcn_mfma_f32_16x16x32_bf16(ah[i], wl[j], acc[i][j], 0, 0, 0);
#pragma unroll
        for (int i = 0; i < 4; ++i)
#pragma unroll
            for (int j = 0; j < 4; ++j)
                acc[i][j] = __builtin_amdgcn_mfma_f32_16x16x32_bf16(al[i], wh[j], acc[i][j], 0, 0, 0);
        __syncthreads();   // protect LDS before next stage
    }

    // ---- epilogue: C/D mapping col=lane&15, row=(lane>>4)*4+reg ----
#pragma unroll
    for (int i = 0; i < 4; ++i)
#pragma unroll
        for (int j = 0; j < 4; ++j) {
#pragma unroll
            for (int r = 0; r < 4; ++r) {
                const int gm = bm + wrow + i * 16 + (lane >> 4) * 4 + r;
                const int gn = bn + wcol + j * 16 + (lane & 15);
                Cp[(size_t)gm * ldc + gn] = acc[i][j][r];
            }
        }
}

// ============================ softmax + attention values ============================
// One block per batch b (768 threads). Sums score partials + bias, per-head
// softmax (3 waves), then v[b, head*768+d] = sum_l a[head][l] * x[b][l][d],
// written directly as split bf16 into the activation buffer.
__global__ __launch_bounds__(768) void attn_kernel(const float* __restrict__ lp,      // [ZA][B][768]
                                                   const float* __restrict__ bias123, // [768]
                                                   const float* __restrict__ x,       // [B][L][D]
                                                   u16* __restrict__ Ahi,             // [B][K_C]
                                                   u16* __restrict__ Alo) {
    __shared__ float sc[3 * Ln];

    const int b = blockIdx.x;
    const int t = threadIdx.x;

    {
        float v = bias123[t];
#pragma unroll
        for (int s = 0; s < ZA; ++s) v += lp[((size_t)s * Bn + b) * N_A + t];
        sc[t] = v;
    }
    __syncthreads();

    const int w = t >> 6, lane = t & 63;
    if (w < 3) {
        float vals[4];
        float m = -3.4e38f;
#pragma unroll
        for (int p = 0; p < 4; ++p) {
            vals[p] = sc[w * 256 + lane + p * 64];
            m = fmaxf(m, vals[p]);
        }
#pragma unroll
        for (int off = 32; off; off >>= 1) m = fmaxf(m, __shfl_xor(m, off));
        float ssum = 0.f;
#pragma unroll
        for (int p = 0; p < 4; ++p) {
            vals[p] = expf(vals[p] - m);
            ssum += vals[p];
        }
#pragma unroll
        for (int off = 32; off; off >>= 1) ssum += __shfl_xor(ssum, off);
        const float inv = 1.0f / ssum;
#pragma unroll
        for (int p = 0; p < 4; ++p) sc[w * 256 + lane + p * 64] = vals[p] * inv;
    }
    __syncthreads();

    float acc0 = 0.f, acc1 = 0.f, acc2 = 0.f;
    const float* xb = x + (size_t)b * Ln * Dn;
#pragma unroll 8
    for (int l = 0; l < Ln; ++l) {
        const float xv = xb[(size_t)l * Dn + t];
        acc0 += sc[l] * xv;
        acc1 += sc[256 + l] * xv;
        acc2 += sc[512 + l] * xv;
    }
    u16* ah = Ahi + (size_t)b * K_C;
    u16* al = Alo + (size_t)b * K_C;
    split2(acc0, ah[t],            al[t]);
    split2(acc1, ah[Dn + t],       al[Dn + t]);
    split2(acc2, ah[2 * Dn + t],   al[2 * Dn + t]);
}

// ============================ LSTM cell elementwise ============================
__global__ __launch_bounds__(256) void lstm_kernel(const float* __restrict__ gp,    // [ZC][B][4096]
                                                   const float* __restrict__ biasC, // [4096]
                                                   float* __restrict__ c,           // [B][H]
                                                   u16* __restrict__ Ahi,           // [B][K_C]
                                                   u16* __restrict__ Alo,
                                                   float* __restrict__ out,         // [B][T][H]
                                                   int tstep) {
    const int gid = blockIdx.x * 256 + threadIdx.x;
    const int b = gid >> 10, j = gid & 1023;

    float ig = biasC[j], fg = biasC[Hn + j], gg = biasC[2 * Hn + j], og = biasC[3 * Hn + j];
#pragma unroll
    for (int s = 0; s < ZC; ++s) {
        const float* g = gp + ((size_t)s * Bn + b) * N_C;
        ig += g[j];
        fg += g[Hn + j];
        gg += g[2 * Hn + j];
        og += g[3 * Hn + j];
    }

    const float i_s = 1.f / (1.f + expf(-ig));
    const float f_s = 1.f / (1.f + expf(-fg));
    const float o_s = 1.f / (1.f + expf(-og));
    const float g_t = tanhf(gg);

    const float ci = c[gid];
    const float cn = f_s * ci + i_s * g_t;
    const float hn = o_s * tanhf(cn);

    c[gid] = cn;
    split2(hn, Ahi[(size_t)b * K_C + 3 * Dn + j], Alo[(size_t)b * K_C + 3 * Dn + j]);
    out[((size_t)b * Tn + tstep) * Hn + j] = hn;
}

// ============================ launch ============================

extern "C" void kernel_launch(void* const* d_in, const int* in_sizes, int n_in,
                              void* d_out, int out_size, void* d_ws, size_t ws_size,
                              hipStream_t stream) {
    const float* x    = (const float*)d_in[0];
    const float* h0   = (const float*)d_in[1];
    const float* c0   = (const float*)d_in[2];
    const float* W1   = (const float*)d_in[3];
    const float* b1   = (const float*)d_in[4];
    const float* W2   = (const float*)d_in[5];
    const float* b2   = (const float*)d_in[6];
    const float* W3   = (const float*)d_in[7];
    const float* b3   = (const float*)d_in[8];
    const float* W_ih = (const float*)d_in[9];
    const float* W_hh = (const float*)d_in[10];
    const float* b_ih = (const float*)d_in[11];
    const float* b_hh = (const float*)d_in[12];
    float* out = (float*)d_out;

    char* ws = (char*)d_ws;
    u16*   WChi    = (u16*)(ws + BY_WCHI);
    u16*   WClo    = (u16*)(ws + BY_WCLO);
    u16*   WAhi    = (u16*)(ws + BY_WAHI);
    u16*   WAlo    = (u16*)(ws + BY_WALO);
    u16*   Ahi     = (u16*)(ws + BY_AHI);
    u16*   Alo     = (u16*)(ws + BY_ALO);
    float* biasC   = (float*)(ws + BY_BIASC);
    float* bias123 = (float*)(ws + BY_B123);
    float* cbuf    = (float*)(ws + BY_C);
    float* lp      = (float*)(ws + BY_LP);
    float* gp      = (float*)(ws + BY_GP);

    // ---- once-per-call prep ----
    prep_wc<<<(int)(((size_t)N_C * K_C) / 256), 256, 0, stream>>>(W_ih, W_hh, WChi, WClo);
    prep_wa<<<(N_A * K_A) / 256, 256, 0, stream>>>(W1, W2, W3, WAhi, WAlo);
    prep_state<<<(Bn * Hn) / 256, 256, 0, stream>>>(h0, c0, b_ih, b_hh, b1, b2, b3,
                                                    Ahi, Alo, cbuf, biasC, bias123);

    // ---- recurrent steps ----
    for (int t = 0; t < Tn; ++t) {
        // Phase A: score logits = h @ [W1|W2|W3]^T  (K=1024, z=4)
        gemm_mfma3<<<dim3(N_A / 128, Bn / 128, ZA), 256, 0, stream>>>(
            Ahi + 3 * Dn, Alo + 3 * Dn, K_C, WAhi, WAlo, K_A,
            lp, N_A, Bn, K_A / ZA, (K_A / ZA) / 32);
        // Phase B: softmax + attention values -> activation cols [0, 2304)
        attn_kernel<<<Bn, 768, 0, stream>>>(lp, bias123, x, Ahi, Alo);
        // Phase C: gates = [v|h] @ [W_ih|W_hh]^T  (K=3328, z=8)
        gemm_mfma3<<<dim3(N_C / 128, Bn / 128, ZC), 256, 0, stream>>>(
            Ahi, Alo, K_C, WChi, WClo, K_C,
            gp, N_C, Bn, K_C / ZC, (K_C / ZC) / 32);
        // Phase D: LSTM cell -> h (split bf16) + out
        lstm_kernel<<<(Bn * Hn) / 256, 256, 0, stream>>>(gp, biasC, cbuf, Ahi, Alo, out, t);
    }

    (void)in_sizes; (void)n_in; (void)out_size; (void)ws_size;
}

// Round 3
// 2997.408 us; speedup vs baseline: 2.2701x; 1.0959x over previous
//
#include <hip/hip_runtime.h>
#include <math.h>

// Problem constants (B, L, D, H, T) — fixed by the reference.
constexpr int Bn = 256;            // batch
constexpr int Ln = 256;            // seq len
constexpr int Dn = 768;            // input size
constexpr int Hn = 1024;           // hidden size
constexpr int Tn = 32;             // output steps

constexpr int K_A = Hn;            // 1024 : K of scores GEMM
constexpr int N_A = 3 * Ln;        // 768  : 3 heads x L
constexpr int K_C = 3 * Dn + Hn;   // 3328 : K of gates GEMM ([v|h])
constexpr int N_C = 4 * Hn;        // 4096 : 4 gates x H

constexpr int ZA = 4;              // K-split of scores GEMM (4 x 256)
constexpr int ZC = 8;              // K-split of gates GEMM (8 x 416)

typedef unsigned short u16;
typedef short bf16x8 __attribute__((ext_vector_type(8)));  // 8 bf16 = 4 VGPRs
typedef float f32x4 __attribute__((ext_vector_type(4)));

// ---- workspace layout (byte offsets) ----
constexpr size_t BY_WCHI  = 0;                                   // [N_C][K_C] bf16 hi
constexpr size_t BY_WCLO  = BY_WCHI  + (size_t)N_C * K_C * 2;    // [N_C][K_C] bf16 lo
constexpr size_t BY_WAHI  = BY_WCLO  + (size_t)N_C * K_C * 2;    // [N_A][K_A] bf16 hi
constexpr size_t BY_WALO  = BY_WAHI  + (size_t)N_A * K_A * 2;    // [N_A][K_A] bf16 lo
constexpr size_t BY_AHI   = BY_WALO  + (size_t)N_A * K_A * 2;    // [B][K_C]  activations hi
constexpr size_t BY_ALO   = BY_AHI   + (size_t)Bn * K_C * 2;     // [B][K_C]  activations lo
constexpr size_t BY_BIASC = BY_ALO   + (size_t)Bn * K_C * 2;     // [N_C] f32
constexpr size_t BY_B123  = BY_BIASC + (size_t)N_C * 4;          // [N_A] f32
constexpr size_t BY_C     = BY_B123  + (size_t)N_A * 4;          // [B][H] f32 cell
constexpr size_t BY_LP    = BY_C     + (size_t)Bn * Hn * 4;      // [ZA][B][N_A] f32
constexpr size_t BY_GP    = BY_LP    + (size_t)ZA * Bn * N_A * 4;// [ZC][B][N_C] f32

// ---- bf16 split helpers ----
__device__ inline u16 f2bf(float f) {
    unsigned int u = __float_as_uint(f);
    u = (u + 0x7fff + ((u >> 16) & 1)) >> 16;   // round-to-nearest-even
    return (u16)u;
}
__device__ inline float bf2f(u16 s) { return __uint_as_float((unsigned int)s << 16); }
__device__ inline void split2(float a, u16& hi, u16& lo) {
    hi = f2bf(a);
    lo = f2bf(a - bf2f(hi));
}

// ============================ prep kernels (once per call) ============================

__global__ __launch_bounds__(256) void prep_wc(const float* __restrict__ W_ih,
                                               const float* __restrict__ W_hh,
                                               u16* __restrict__ Whi, u16* __restrict__ Wlo) {
    size_t id = (size_t)blockIdx.x * 256 + threadIdx.x;   // over N_C*K_C
    int n = (int)(id / K_C), j = (int)(id % K_C);
    float v = (j < 3 * Dn) ? W_ih[(size_t)n * (3 * Dn) + j]
                           : W_hh[(size_t)n * Hn + (j - 3 * Dn)];
    split2(v, Whi[id], Wlo[id]);
}

__global__ __launch_bounds__(256) void prep_wa(const float* __restrict__ W1,
                                               const float* __restrict__ W2,
                                               const float* __restrict__ W3,
                                               u16* __restrict__ Whi, u16* __restrict__ Wlo) {
    int id = blockIdx.x * 256 + threadIdx.x;              // over N_A*K_A
    int c = id >> 10, d = id & 1023;                      // row c = head*256+l
    int k = c >> 8, l = c & 255;
    const float* Wk = (k == 0) ? W1 : ((k == 1) ? W2 : W3);
    split2(Wk[l * Hn + d], Whi[id], Wlo[id]);
}

__global__ __launch_bounds__(256) void prep_state(const float* __restrict__ h0,
                                                  const float* __restrict__ c0,
                                                  const float* __restrict__ b_ih,
                                                  const float* __restrict__ b_hh,
                                                  const float* __restrict__ b1,
                                                  const float* __restrict__ b2,
                                                  const float* __restrict__ b3,
                                                  u16* __restrict__ Ahi, u16* __restrict__ Alo,
                                                  float* __restrict__ c,
                                                  float* __restrict__ biasC,
                                                  float* __restrict__ bias123) {
    int gid = blockIdx.x * 256 + threadIdx.x;             // grid covers B*H
    int b = gid >> 10, j = gid & 1023;
    split2(h0[gid], Ahi[(size_t)b * K_C + 3 * Dn + j], Alo[(size_t)b * K_C + 3 * Dn + j]);
    c[gid] = c0[gid];
    if (gid < N_C) biasC[gid] = b_ih[gid] + b_hh[gid];
    if (gid < N_A) {
        int k = gid >> 8, l = gid & 255;
        bias123[gid] = (k == 0 ? b1 : (k == 1 ? b2 : b3))[l];
    }
}

// ============================ split-bf16 MFMA GEMM ============================
// Cp[z] = Ahi*Whi^T + Ahi*Wlo^T + Alo*Whi^T over K-slice z (fp32-grade accuracy).
// 128x128 tile, BK=32, 4 waves (64x64 quadrant each). Double-buffered LDS
// (prefetch k-step t+1 during compute of t, ONE barrier per k-step), and a
// source-side XOR swizzle (rule #21: gload_lds dest must stay linear, so the
// 16B-chunk permutation is applied to the per-lane GLOBAL address and to the
// ds_read slot): LDS(row, slot) holds global chunk slot^(row&3). This turns
// the 8-way bank conflict of 64B-row fragment reads into a free 2-way.
__device__ inline void gload16(const u16* g, u16* l) {
    __builtin_amdgcn_global_load_lds(
        (const __attribute__((address_space(1))) unsigned int*)g,
        (__attribute__((address_space(3))) unsigned int*)l, 16, 0, 0);
}

__global__ __launch_bounds__(256) void gemm_mfma3(const u16* __restrict__ Ahi,
                                                  const u16* __restrict__ Alo, int lda,
                                                  const u16* __restrict__ Whi,
                                                  const u16* __restrict__ Wlo, int ldw,
                                                  float* __restrict__ Cp, int ldc, int mtot,
                                                  int ksub, int nkstep) {
    __shared__ u16 smem[2 * 4 * 4096];   // [buf][tile: Ahi,Alo,Whi,Wlo][128*32] = 64 KB

    const int t = threadIdx.x;
    const int w = t >> 6, lane = t & 63;
    const int bm = blockIdx.y * 128;
    const int bn = blockIdx.x * 128;
    const int k00 = blockIdx.z * ksub;
    Cp += (size_t)blockIdx.z * mtot * ldc;

    // staging role: wave w owns tile w (Ahi, Alo, Whi, Wlo)
    const u16* gsrc;
    int ld, rb;
    if      (w == 0) { gsrc = Ahi; ld = lda; rb = bm; }
    else if (w == 1) { gsrc = Alo; ld = lda; rb = bm; }
    else if (w == 2) { gsrc = Whi; ld = ldw; rb = bn; }
    else             { gsrc = Wlo; ld = ldw; rb = bn; }
    const int srow  = lane >> 2;                           // row within 16-row chunk
    const int scol8 = (((lane & 3) ^ ((lane >> 2) & 3)) * 8); // pre-swizzled k-chunk (u16 units)

    const int wrow = (w >> 1) * 64;      // wave's output quadrant
    const int wcol = (w & 1) * 64;
    const int fr = lane & 15;            // fragment row/col within 16
    const int slot = ((lane >> 4) ^ (fr & 3)) * 8;  // swizzled read chunk (u16 units)

    auto stage = [&](int ks, u16* dstbuf) {
        const int k0 = k00 + ks * 32;
        u16* dst = dstbuf + w * 4096;
#pragma unroll
        for (int i = 0; i < 8; ++i) {
            const u16* p = gsrc + (size_t)(rb + i * 16 + srow) * ld + k0 + scol8;
            gload16(p, dst + i * 512);
        }
    };

    f32x4 acc[4][4] = {};

    // prologue: stage k-step 0 into buf 0
    stage(0, smem);
    __syncthreads();

    for (int ks = 0; ks < nkstep; ++ks) {
        const int cur = ks & 1;
        u16* bufc = smem + cur * 16384;
        if (ks + 1 < nkstep) stage(ks + 1, smem + (cur ^ 1) * 16384);

        // ---- LDS -> fragments (swizzled slot) ----
        bf16x8 ah[4], al[4], wh[4], wl[4];
#pragma unroll
        for (int f = 0; f < 4; ++f) {
            const int ra = (wrow + f * 16 + fr) * 32;
            const int rw = (wcol + f * 16 + fr) * 32;
            ah[f] = *(const bf16x8*)&bufc[0 * 4096 + ra + slot];
            al[f] = *(const bf16x8*)&bufc[1 * 4096 + ra + slot];
            wh[f] = *(const bf16x8*)&bufc[2 * 4096 + rw + slot];
            wl[f] = *(const bf16x8*)&bufc[3 * 4096 + rw + slot];
        }
        // ---- 48 MFMA: hi*hi + hi*lo + lo*hi ----
#pragma unroll
        for (int i = 0; i < 4; ++i)
#pragma unroll
            for (int j = 0; j < 4; ++j)
                acc[i][j] = __builtin_amdgcn_mfma_f32_16x16x32_bf16(ah[i], wh[j], acc[i][j], 0, 0, 0);
#pragma unroll
        for (int i = 0; i < 4; ++i)
#pragma unroll
            for (int j = 0; j < 4; ++j)
                acc[i][j] = __builtin_amdgcn_mfma_f32_16x16x32_bf16(ah[i], wl[j], acc[i][j], 0, 0, 0);
#pragma unroll
        for (int i = 0; i < 4; ++i)
#pragma unroll
            for (int j = 0; j < 4; ++j)
                acc[i][j] = __builtin_amdgcn_mfma_f32_16x16x32_bf16(al[i], wh[j], acc[i][j], 0, 0, 0);

        __syncthreads();   // drains prefetch (vmcnt) + protects both buffers
    }

    // ---- epilogue: C/D mapping col=lane&15, row=(lane>>4)*4+reg ----
#pragma unroll
    for (int i = 0; i < 4; ++i)
#pragma unroll
        for (int j = 0; j < 4; ++j) {
#pragma unroll
            for (int r = 0; r < 4; ++r) {
                const int gm = bm + wrow + i * 16 + (lane >> 4) * 4 + r;
                const int gn = bn + wcol + j * 16 + (lane & 15);
                Cp[(size_t)gm * ldc + gn] = acc[i][j][r];
            }
        }
}

// ============================ softmax + attention values ============================
// One block per batch b (768 threads). Sums score partials + bias, per-head
// softmax (3 waves), then v[b, head*768+d] = sum_l a[head][l] * x[b][l][d].
// x is streamed as float4 by 192-lane column groups x 4 row-groups, with an
// LDS partial reduction; v written directly as split bf16.
__global__ __launch_bounds__(768) void attn_kernel(const float* __restrict__ lp,      // [ZA][B][768]
                                                   const float* __restrict__ bias123, // [768]
                                                   const float* __restrict__ x,       // [B][L][D]
                                                   u16* __restrict__ Ahi,             // [B][K_C]
                                                   u16* __restrict__ Alo) {
    __shared__ float sc[3 * Ln];          // 3 KB logits -> probs
    __shared__ float pad[4][3 * Dn];      // 36 KB partial v sums

    const int b = blockIdx.x;
    const int t = threadIdx.x;

    {
        float v = bias123[t];
#pragma unroll
        for (int s = 0; s < ZA; ++s) v += lp[((size_t)s * Bn + b) * N_A + t];
        sc[t] = v;
    }
    __syncthreads();

    const int w = t >> 6, lane = t & 63;
    if (w < 3) {
        float vals[4];
        float m = -3.4e38f;
#pragma unroll
        for (int p = 0; p < 4; ++p) {
            vals[p] = sc[w * 256 + lane + p * 64];
            m = fmaxf(m, vals[p]);
        }
#pragma unroll
        for (int off = 32; off; off >>= 1) m = fmaxf(m, __shfl_xor(m, off));
        float ssum = 0.f;
#pragma unroll
        for (int p = 0; p < 4; ++p) {
            vals[p] = expf(vals[p] - m);
            ssum += vals[p];
        }
#pragma unroll
        for (int off = 32; off; off >>= 1) ssum += __shfl_xor(ssum, off);
        const float inv = 1.0f / ssum;
#pragma unroll
        for (int p = 0; p < 4; ++p) sc[w * 256 + lane + p * 64] = vals[p] * inv;
    }
    __syncthreads();

    // vectorized weighted sum: col4 = 4 columns, grp = row-group (l = grp mod 4)
    const int col4 = (t % 192) * 4;
    const int grp  = t / 192;
    float4 a0 = {0, 0, 0, 0}, a1 = {0, 0, 0, 0}, a2 = {0, 0, 0, 0};
    const float* xb = x + (size_t)b * Ln * Dn;
#pragma unroll 8
    for (int l = grp; l < Ln; l += 4) {
        const float4 xv = *reinterpret_cast<const float4*>(&xb[(size_t)l * Dn + col4]);
        const float s0 = sc[l], s1 = sc[256 + l], s2 = sc[512 + l];
        a0.x += s0 * xv.x; a0.y += s0 * xv.y; a0.z += s0 * xv.z; a0.w += s0 * xv.w;
        a1.x += s1 * xv.x; a1.y += s1 * xv.y; a1.z += s1 * xv.z; a1.w += s1 * xv.w;
        a2.x += s2 * xv.x; a2.y += s2 * xv.y; a2.z += s2 * xv.z; a2.w += s2 * xv.w;
    }
    *reinterpret_cast<float4*>(&pad[grp][0 * Dn + col4]) = a0;
    *reinterpret_cast<float4*>(&pad[grp][1 * Dn + col4]) = a1;
    *reinterpret_cast<float4*>(&pad[grp][2 * Dn + col4]) = a2;
    __syncthreads();

    // cross-group reduce: thread t owns column t for all 3 heads
    u16* ah = Ahi + (size_t)b * K_C;
    u16* al = Alo + (size_t)b * K_C;
#pragma unroll
    for (int h = 0; h < 3; ++h) {
        const float v = pad[0][h * Dn + t] + pad[1][h * Dn + t] +
                        pad[2][h * Dn + t] + pad[3][h * Dn + t];
        split2(v, ah[h * Dn + t], al[h * Dn + t]);
    }
}

// ============================ LSTM cell elementwise ============================
__global__ __launch_bounds__(256) void lstm_kernel(const float* __restrict__ gp,    // [ZC][B][4096]
                                                   const float* __restrict__ biasC, // [4096]
                                                   float* __restrict__ c,           // [B][H]
                                                   u16* __restrict__ Ahi,           // [B][K_C]
                                                   u16* __restrict__ Alo,
                                                   float* __restrict__ out,         // [B][T][H]
                                                   int tstep) {
    const int gid = blockIdx.x * 256 + threadIdx.x;
    const int b = gid >> 10, j = gid & 1023;

    float ig = biasC[j], fg = biasC[Hn + j], gg = biasC[2 * Hn + j], og = biasC[3 * Hn + j];
#pragma unroll
    for (int s = 0; s < ZC; ++s) {
        const float* g = gp + ((size_t)s * Bn + b) * N_C;
        ig += g[j];
        fg += g[Hn + j];
        gg += g[2 * Hn + j];
        og += g[3 * Hn + j];
    }

    const float i_s = 1.f / (1.f + expf(-ig));
    const float f_s = 1.f / (1.f + expf(-fg));
    const float o_s = 1.f / (1.f + expf(-og));
    const float g_t = tanhf(gg);

    const float ci = c[gid];
    const float cn = f_s * ci + i_s * g_t;
    const float hn = o_s * tanhf(cn);

    c[gid] = cn;
    split2(hn, Ahi[(size_t)b * K_C + 3 * Dn + j], Alo[(size_t)b * K_C + 3 * Dn + j]);
    out[((size_t)b * Tn + tstep) * Hn + j] = hn;
}

// ============================ launch ============================

extern "C" void kernel_launch(void* const* d_in, const int* in_sizes, int n_in,
                              void* d_out, int out_size, void* d_ws, size_t ws_size,
                              hipStream_t stream) {
    const float* x    = (const float*)d_in[0];
    const float* h0   = (const float*)d_in[1];
    const float* c0   = (const float*)d_in[2];
    const float* W1   = (const float*)d_in[3];
    const float* b1   = (const float*)d_in[4];
    const float* W2   = (const float*)d_in[5];
    const float* b2   = (const float*)d_in[6];
    const float* W3   = (const float*)d_in[7];
    const float* b3   = (const float*)d_in[8];
    const float* W_ih = (const float*)d_in[9];
    const float* W_hh = (const float*)d_in[10];
    const float* b_ih = (const float*)d_in[11];
    const float* b_hh = (const float*)d_in[12];
    float* out = (float*)d_out;

    char* ws = (char*)d_ws;
    u16*   WChi    = (u16*)(ws + BY_WCHI);
    u16*   WClo    = (u16*)(ws + BY_WCLO);
    u16*   WAhi    = (u16*)(ws + BY_WAHI);
    u16*   WAlo    = (u16*)(ws + BY_WALO);
    u16*   Ahi     = (u16*)(ws + BY_AHI);
    u16*   Alo     = (u16*)(ws + BY_ALO);
    float* biasC   = (float*)(ws + BY_BIASC);
    float* bias123 = (float*)(ws + BY_B123);
    float* cbuf    = (float*)(ws + BY_C);
    float* lp      = (float*)(ws + BY_LP);
    float* gp      = (float*)(ws + BY_GP);

    // ---- once-per-call prep ----
    prep_wc<<<(int)(((size_t)N_C * K_C) / 256), 256, 0, stream>>>(W_ih, W_hh, WChi, WClo);
    prep_wa<<<(N_A * K_A) / 256, 256, 0, stream>>>(W1, W2, W3, WAhi, WAlo);
    prep_state<<<(Bn * Hn) / 256, 256, 0, stream>>>(h0, c0, b_ih, b_hh, b1, b2, b3,
                                                    Ahi, Alo, cbuf, biasC, bias123);

    // ---- recurrent steps ----
    for (int t = 0; t < Tn; ++t) {
        // Phase A: score logits = h @ [W1|W2|W3]^T  (K=1024, z=4)
        gemm_mfma3<<<dim3(N_A / 128, Bn / 128, ZA), 256, 0, stream>>>(
            Ahi + 3 * Dn, Alo + 3 * Dn, K_C, WAhi, WAlo, K_A,
            lp, N_A, Bn, K_A / ZA, (K_A / ZA) / 32);
        // Phase B: softmax + attention values -> activation cols [0, 2304)
        attn_kernel<<<Bn, 768, 0, stream>>>(lp, bias123, x, Ahi, Alo);
        // Phase C: gates = [v|h] @ [W_ih|W_hh]^T  (K=3328, z=8)
        gemm_mfma3<<<dim3(N_C / 128, Bn / 128, ZC), 256, 0, stream>>>(
            Ahi, Alo, K_C, WChi, WClo, K_C,
            gp, N_C, Bn, K_C / ZC, (K_C / ZC) / 32);
        // Phase D: LSTM cell -> h (split bf16) + out
        lstm_kernel<<<(Bn * Hn) / 256, 256, 0, stream>>>(gp, biasC, cbuf, Ahi, Alo, out, t);
    }

    (void)in_sizes; (void)n_in; (void)out_size; (void)ws_size;
}